// Round 2
// baseline (971.827 us; speedup 1.0000x reference)
//
#include <hip/hip_runtime.h>
#include <math.h>

#define BLK  256
#define DD   128
#define NN   15
#define NL   16
#define OC   16
#define WSTR 260   // per-leaf stride (floats) in sWl chunk: 16*16 + 4 pad

__global__ __launch_bounds__(BLK, 2)
void dts_fused2(const float* __restrict__ x, const float* __restrict__ Wn,
                const float* __restrict__ bn, const float* __restrict__ Wl,
                const float* __restrict__ bl, float* __restrict__ out, int B)
{
    __shared__ __align__(16) float sWl[2][NL * WSTR];   // 33280 B, double-buffered Wl chunk
    __shared__ float sBn[NN];
    __shared__ __align__(16) float sBl[NL * OC];

    float* sWnT = &sWl[0][0];   // [15][128] floats — phase-1 only, aliased into buf0

    const int t = threadIdx.x;
    const int row = blockIdx.x * BLK + t;
    const int rowL = (row < B) ? row : 0;

    // ---- cooperative stage: Wn^T, bn, bl ----
    for (int i = t; i < NN * DD; i += BLK) {
        int n = i >> 7, d = i & 127;       // sWnT[n][d]
        sWnT[i] = Wn[d * NN + n];          // Wn is [D][NN]
    }
    if (t < NN) sBn[t] = bn[t];
    for (int i = t; i < NL * OC; i += BLK) sBl[i] = bl[i];
    __syncthreads();

    // ---- x row into registers (all indices static) ----
    float xs[DD];
    {
        const float4* xr = reinterpret_cast<const float4*>(x + (size_t)rowL * DD);
        #pragma unroll
        for (int q = 0; q < DD / 4; ++q) {
            float4 v = xr[q];
            xs[q*4+0] = v.x; xs[q*4+1] = v.y; xs[q*4+2] = v.z; xs[q*4+3] = v.w;
        }
    }

    // ---- Wl chunk staging lanes: thread t owns leaf t>>4, 16 floats at (t&15)*16 ----
    const float* gw = Wl + ((size_t)(t >> 4) * (DD * OC) + (t & 15) * 16);
    const int stofs = (t >> 4) * WSTR + (t & 15) * 16;
    float4 sg0, sg1, sg2, sg3;
    #define STAGE_LOAD(cc) { const float* g_ = gw + (cc) * 256;                    \
        sg0 = *(const float4*)(g_);      sg1 = *(const float4*)(g_ + 4);           \
        sg2 = *(const float4*)(g_ + 8);  sg3 = *(const float4*)(g_ + 12); }
    #define STAGE_WRITE(bb) { float* d_ = &sWl[bb][stofs];                         \
        *(float4*)(d_)      = sg0; *(float4*)(d_ + 4)  = sg1;                      \
        *(float4*)(d_ + 8)  = sg2; *(float4*)(d_ + 12) = sg3; }

    STAGE_LOAD(0);   // in flight under phase 1

    // ---- phase 1: 15 node dots (sWnT reads are wave-uniform → broadcast) ----
    float acc[NN];
    #pragma unroll
    for (int n = 0; n < NN; ++n) acc[n] = 0.f;
    #pragma unroll
    for (int q = 0; q < DD / 4; ++q) {
        #pragma unroll
        for (int n = 0; n < NN; ++n) {
            const float4 w = *(const float4*)&sWnT[n * DD + q * 4];
            acc[n] = fmaf(xs[q*4+3], w.w, fmaf(xs[q*4+2], w.z,
                     fmaf(xs[q*4+1], w.y, fmaf(xs[q*4+0], w.x, acc[n]))));
        }
    }
    #pragma unroll
    for (int n = 0; n < NN; ++n) acc[n] += sBn[n];

    // ---- tree expand (leaf bits MSB-first, bit0 = left = +) + argmax ----
    float L2a[4], L3a[8], L4a[16];
    {
        float p = acc[0], m = -acc[0];
        L2a[0] = p + acc[1]; L2a[1] = p - acc[1];
        L2a[2] = m + acc[2]; L2a[3] = m - acc[2];
        #pragma unroll
        for (int i = 0; i < 4; ++i) { L3a[2*i] = L2a[i] + acc[3+i]; L3a[2*i+1] = L2a[i] - acc[3+i]; }
        #pragma unroll
        for (int i = 0; i < 8; ++i) { L4a[2*i] = L3a[i] + acc[7+i]; L4a[2*i+1] = L3a[i] - acc[7+i]; }
    }
    int best = 0; float bv = L4a[0];
    #pragma unroll
    for (int l = 1; l < NL; ++l) if (L4a[l] > bv) { bv = L4a[l]; best = l; }

    // ---- output accumulators init from bias ----
    float4 o0, o1, o2, o3;
    {
        const float4* blv = reinterpret_cast<const float4*>(&sBl[best * OC]);
        o0 = blv[0]; o1 = blv[1]; o2 = blv[2]; o3 = blv[3];
    }
    const int wlofs = best * WSTR;

    __syncthreads();       // phase-1 sWnT reads complete before overwriting buf0
    STAGE_WRITE(0);
    STAGE_LOAD(1);
    __syncthreads();       // buf0 visible

    // ---- phase 3: 8 chunks of 16 dims, double-buffered ----
    #pragma unroll
    for (int c = 0; c < 8; ++c) {
        const float* wb = &sWl[c & 1][wlofs];
        #pragma unroll
        for (int k = 0; k < 16; ++k) {
            const float4 w0 = *(const float4*)&wb[k * 16 + 0];
            const float4 w1 = *(const float4*)&wb[k * 16 + 4];
            const float4 w2 = *(const float4*)&wb[k * 16 + 8];
            const float4 w3 = *(const float4*)&wb[k * 16 + 12];
            const float xv = xs[c * 16 + k];
            o0.x = fmaf(xv, w0.x, o0.x); o0.y = fmaf(xv, w0.y, o0.y);
            o0.z = fmaf(xv, w0.z, o0.z); o0.w = fmaf(xv, w0.w, o0.w);
            o1.x = fmaf(xv, w1.x, o1.x); o1.y = fmaf(xv, w1.y, o1.y);
            o1.z = fmaf(xv, w1.z, o1.z); o1.w = fmaf(xv, w1.w, o1.w);
            o2.x = fmaf(xv, w2.x, o2.x); o2.y = fmaf(xv, w2.y, o2.y);
            o2.z = fmaf(xv, w2.z, o2.z); o2.w = fmaf(xv, w2.w, o2.w);
            o3.x = fmaf(xv, w3.x, o3.x); o3.y = fmaf(xv, w3.y, o3.y);
            o3.z = fmaf(xv, w3.z, o3.z); o3.w = fmaf(xv, w3.w, o3.w);
        }
        if (c < 7) {
            STAGE_WRITE((c + 1) & 1);          // prev readers of this buf barriered last iter
            if (c < 6) STAGE_LOAD(c + 2);
            __syncthreads();                    // writes visible for iter c+1
        }
    }
    #undef STAGE_LOAD
    #undef STAGE_WRITE

    // ---- store (coalesced, no permute) ----
    if (row < B) {
        size_t ob = (size_t)row * 8;
        *reinterpret_cast<float4*>(&out[ob])     = o0;
        *reinterpret_cast<float4*>(&out[ob + 4]) = o1;

        // log_std = -5 + 3.5*(tanh(v)+1) = -1.5 + 3.5*tanh(v); tanh = 1 - 2/(e^{2v}+1)
        float4 r0, r1;
        #define SQ(v) (-1.5f + 3.5f * (1.f - 2.f / (__expf(2.f * (v)) + 1.f)))
        r0.x = SQ(o2.x); r0.y = SQ(o2.y); r0.z = SQ(o2.z); r0.w = SQ(o2.w);
        r1.x = SQ(o3.x); r1.y = SQ(o3.y); r1.z = SQ(o3.z); r1.w = SQ(o3.w);
        #undef SQ
        size_t ob2 = (size_t)B * 8 + ob;
        *reinterpret_cast<float4*>(&out[ob2])     = r0;
        *reinterpret_cast<float4*>(&out[ob2 + 4]) = r1;
    }
}

extern "C" void kernel_launch(void* const* d_in, const int* in_sizes, int n_in,
                              void* d_out, int out_size, void* d_ws, size_t ws_size,
                              hipStream_t stream)
{
    const float* x  = (const float*)d_in[0];
    const float* Wn = (const float*)d_in[1];
    const float* bn = (const float*)d_in[2];
    const float* Wl = (const float*)d_in[3];
    const float* bl = (const float*)d_in[4];
    float* out = (float*)d_out;

    const int B = in_sizes[0] / DD;              // 262144
    const int blocks = (B + BLK - 1) / BLK;      // 1024

    hipLaunchKernelGGL(dts_fused2, dim3(blocks), dim3(BLK), 0, stream,
                       x, Wn, bn, Wl, bl, out, B);
}

// Round 3
// 934.596 us; speedup vs baseline: 1.0398x; 1.0398x over previous
//
#include <hip/hip_runtime.h>
#include <math.h>

#define BLK  256
#define DD   128
#define NN   15
#define NL   16
#define OC   16
#define WSTR 260   // per-leaf stride (floats): 256 + 4 pad -> leaf starts spread over 8 banks

__global__ __launch_bounds__(BLK, 4)
void dts_fused3(const float* __restrict__ x, const float* __restrict__ Wn,
                const float* __restrict__ bn, const float* __restrict__ Wl,
                const float* __restrict__ bl, float* __restrict__ out, int B)
{
    __shared__ __align__(16) float sWl[2][NL * WSTR];   // 33280 B double-buffered Wl chunk
    __shared__ float sBn[NN];
    __shared__ __align__(16) float sBl[NL * OC];

    float* sWnT = &sWl[0][0];   // [15][128] — phase-1 only, aliased into buf0

    const int t = threadIdx.x;
    const int row = blockIdx.x * BLK + t;
    const int rowL = (row < B) ? row : 0;
    const float4* xr = reinterpret_cast<const float4*>(x + (size_t)rowL * DD);

    // ---- cooperative stage: Wn^T, bn, bl ----
    for (int i = t; i < NN * DD; i += BLK) {
        int n = i >> 7, d = i & 127;       // sWnT[n][d]
        sWnT[i] = Wn[d * NN + n];          // Wn is [D][NN]
    }
    if (t < NN) sBn[t] = bn[t];
    for (int i = t; i < NL * OC; i += BLK) sBl[i] = bl[i];

    // ---- Wl staging: thread t owns leaf t>>4, 16 floats at dim-block (t&15) ----
    const float* gw = Wl + ((size_t)(t >> 4) * (DD * OC) + (t & 15) * 16);
    const int stofs = (t >> 4) * WSTR + (t & 15) * 16;
    float4 sa0, sa1, sa2, sa3;   // staging set A (even chunks)
    float4 sb0, sb1, sb2, sb3;   // staging set B (odd chunks)

    #define LOAD_A(cc) { const float* g_ = gw + (cc) * 256;                      \
        sa0 = *(const float4*)(g_);      sa1 = *(const float4*)(g_ + 4);         \
        sa2 = *(const float4*)(g_ + 8);  sa3 = *(const float4*)(g_ + 12); }
    #define LOAD_B(cc) { const float* g_ = gw + (cc) * 256;                      \
        sb0 = *(const float4*)(g_);      sb1 = *(const float4*)(g_ + 4);         \
        sb2 = *(const float4*)(g_ + 8);  sb3 = *(const float4*)(g_ + 12); }
    #define WRITE_A(bb) { float* d_ = &sWl[bb][stofs];                           \
        *(float4*)(d_)      = sa0; *(float4*)(d_ + 4)  = sa1;                    \
        *(float4*)(d_ + 8)  = sa2; *(float4*)(d_ + 12) = sa3; }
    #define WRITE_B(bb) { float* d_ = &sWl[bb][stofs];                           \
        *(float4*)(d_)      = sb0; *(float4*)(d_ + 4)  = sb1;                    \
        *(float4*)(d_ + 8)  = sb2; *(float4*)(d_ + 12) = sb3; }

    LOAD_A(0);                 // in flight under phase 1
    __syncthreads();           // sWnT / sBn / sBl ready

    // ---- phase 1: 15 node dots; x streamed, consumed on the fly ----
    float acc[NN];
    #pragma unroll
    for (int n = 0; n < NN; ++n) acc[n] = 0.f;
    #pragma unroll
    for (int q = 0; q < DD / 4; ++q) {
        const float4 xv = xr[q];
        #pragma unroll
        for (int n = 0; n < NN; ++n) {
            const float4 w = *(const float4*)&sWnT[n * DD + q * 4];
            acc[n] = fmaf(xv.w, w.w, fmaf(xv.z, w.z,
                     fmaf(xv.y, w.y, fmaf(xv.x, w.x, acc[n]))));
        }
    }
    #pragma unroll
    for (int n = 0; n < NN; ++n) acc[n] += sBn[n];

    // ---- tree expand (leaf bits MSB-first, bit0 = left = +) + argmax ----
    float L2a[4], L3a[8], L4a[16];
    {
        float p = acc[0], m = -acc[0];
        L2a[0] = p + acc[1]; L2a[1] = p - acc[1];
        L2a[2] = m + acc[2]; L2a[3] = m - acc[2];
        #pragma unroll
        for (int i = 0; i < 4; ++i) { L3a[2*i] = L2a[i] + acc[3+i]; L3a[2*i+1] = L2a[i] - acc[3+i]; }
        #pragma unroll
        for (int i = 0; i < 8; ++i) { L4a[2*i] = L3a[i] + acc[7+i]; L4a[2*i+1] = L3a[i] - acc[7+i]; }
    }
    int best = 0; float bv = L4a[0];
    #pragma unroll
    for (int l = 1; l < NL; ++l) if (L4a[l] > bv) { bv = L4a[l]; best = l; }

    // ---- init out accumulators from bias ----
    float4 o0, o1, o2, o3;
    {
        const float4* blv = reinterpret_cast<const float4*>(&sBl[best * OC]);
        o0 = blv[0]; o1 = blv[1]; o2 = blv[2]; o3 = blv[3];
    }
    const int wlofs = best * WSTR;

    float4 xc0, xc1, xc2, xc3, xn0, xn1, xn2, xn3;

    __syncthreads();           // phase-1 sWnT readers done before overwriting buf0
    WRITE_A(0);
    LOAD_B(1);
    xc0 = xr[0]; xc1 = xr[1]; xc2 = xr[2]; xc3 = xr[3];   // L2-hot re-read, chunk 0
    __syncthreads();           // buf0 visible

    // ---- phase 3: 8 chunks of 16 dims, double-buffered ----
    #pragma unroll
    for (int c = 0; c < 8; ++c) {
        if (c < 7) {           // prefetch next x chunk (one 64B line per lane)
            xn0 = xr[(c+1)*4+0]; xn1 = xr[(c+1)*4+1];
            xn2 = xr[(c+1)*4+2]; xn3 = xr[(c+1)*4+3];
        }
        const float* wb = &sWl[c & 1][wlofs];
        #define KSTEP(xv, k) { \
            const float4 w0 = *(const float4*)&wb[(k) * 16 + 0];  \
            const float4 w1 = *(const float4*)&wb[(k) * 16 + 4];  \
            const float4 w2 = *(const float4*)&wb[(k) * 16 + 8];  \
            const float4 w3 = *(const float4*)&wb[(k) * 16 + 12]; \
            o0.x = fmaf((xv), w0.x, o0.x); o0.y = fmaf((xv), w0.y, o0.y); \
            o0.z = fmaf((xv), w0.z, o0.z); o0.w = fmaf((xv), w0.w, o0.w); \
            o1.x = fmaf((xv), w1.x, o1.x); o1.y = fmaf((xv), w1.y, o1.y); \
            o1.z = fmaf((xv), w1.z, o1.z); o1.w = fmaf((xv), w1.w, o1.w); \
            o2.x = fmaf((xv), w2.x, o2.x); o2.y = fmaf((xv), w2.y, o2.y); \
            o2.z = fmaf((xv), w2.z, o2.z); o2.w = fmaf((xv), w2.w, o2.w); \
            o3.x = fmaf((xv), w3.x, o3.x); o3.y = fmaf((xv), w3.y, o3.y); \
            o3.z = fmaf((xv), w3.z, o3.z); o3.w = fmaf((xv), w3.w, o3.w); }
        KSTEP(xc0.x,  0) KSTEP(xc0.y,  1) KSTEP(xc0.z,  2) KSTEP(xc0.w,  3)
        KSTEP(xc1.x,  4) KSTEP(xc1.y,  5) KSTEP(xc1.z,  6) KSTEP(xc1.w,  7)
        KSTEP(xc2.x,  8) KSTEP(xc2.y,  9) KSTEP(xc2.z, 10) KSTEP(xc2.w, 11)
        KSTEP(xc3.x, 12) KSTEP(xc3.y, 13) KSTEP(xc3.z, 14) KSTEP(xc3.w, 15)
        #undef KSTEP

        if (c < 7) {
            // write chunk c+1 into the other buffer (its readers barriered at iter c-1),
            // then issue the global load for chunk c+2 into the freed staging set.
            if ((c & 1) == 0) { WRITE_B((c + 1) & 1); if (c < 6) LOAD_A(c + 2); }
            else              { WRITE_A((c + 1) & 1); if (c < 6) LOAD_B(c + 2); }
            __syncthreads();   // chunk c+1 visible
            xc0 = xn0; xc1 = xn1; xc2 = xn2; xc3 = xn3;
        }
    }
    #undef LOAD_A
    #undef LOAD_B
    #undef WRITE_A
    #undef WRITE_B

    // ---- store (coalesced) ----
    if (row < B) {
        size_t ob = (size_t)row * 8;
        *reinterpret_cast<float4*>(&out[ob])     = o0;
        *reinterpret_cast<float4*>(&out[ob + 4]) = o1;

        // log_std = -5 + 3.5*(tanh(v)+1) = -1.5 + 3.5*tanh(v); tanh = 1 - 2/(e^{2v}+1)
        float4 r0, r1;
        #define SQ(v) (-1.5f + 3.5f * (1.f - 2.f / (__expf(2.f * (v)) + 1.f)))
        r0.x = SQ(o2.x); r0.y = SQ(o2.y); r0.z = SQ(o2.z); r0.w = SQ(o2.w);
        r1.x = SQ(o3.x); r1.y = SQ(o3.y); r1.z = SQ(o3.z); r1.w = SQ(o3.w);
        #undef SQ
        size_t ob2 = (size_t)B * 8 + ob;
        *reinterpret_cast<float4*>(&out[ob2])     = r0;
        *reinterpret_cast<float4*>(&out[ob2 + 4]) = r1;
    }
}

extern "C" void kernel_launch(void* const* d_in, const int* in_sizes, int n_in,
                              void* d_out, int out_size, void* d_ws, size_t ws_size,
                              hipStream_t stream)
{
    const float* x  = (const float*)d_in[0];
    const float* Wn = (const float*)d_in[1];
    const float* bn = (const float*)d_in[2];
    const float* Wl = (const float*)d_in[3];
    const float* bl = (const float*)d_in[4];
    float* out = (float*)d_out;

    const int B = in_sizes[0] / DD;              // 262144
    const int blocks = (B + BLK - 1) / BLK;      // 1024

    hipLaunchKernelGGL(dts_fused3, dim3(blocks), dim3(BLK), 0, stream,
                       x, Wn, bn, Wl, bl, out, B);
}

// Round 4
// 71.029 us; speedup vs baseline: 13.6821x; 13.1579x over previous
//
#include <hip/hip_runtime.h>
#include <math.h>

#define BLK  256
#define DD   128
#define NN   15
#define NL   16
#define OC   16
#define WSTR 260   // per-leaf LDS stride (floats): 256 + 4 -> leaf bases spread across banks

__global__ __launch_bounds__(BLK, 6)
void dts_fused4(const float* __restrict__ x, const float* __restrict__ Wn,
                const float* __restrict__ bn, const float* __restrict__ Wl,
                const float* __restrict__ bl, float* __restrict__ out, int B)
{
    __shared__ __align__(16) float sWnT[NN * DD];     // 7680 B
    __shared__ __align__(16) float sWl[NL * WSTR];    // 16640 B, single-buffered chunk
    __shared__ float sBn[NN];
    __shared__ __align__(16) float sBl[NL * OC];

    const int t = threadIdx.x;
    const int row = blockIdx.x * BLK + t;
    const int rowL = (row < B) ? row : 0;
    const float4* xr = reinterpret_cast<const float4*>(x + (size_t)rowL * DD);

    // ---- cooperative stage: Wn^T, bn, bl ----
    for (int i = t; i < NN * DD; i += BLK) {
        int n = i >> 7, d = i & 127;       // sWnT[n][d]
        sWnT[i] = Wn[d * NN + n];          // Wn is [D][NN]
    }
    if (t < NN) sBn[t] = bn[t];
    for (int i = t; i < NL * OC; i += BLK) sBl[i] = bl[i];
    __syncthreads();

    // ---- phase 1: 15 node dots; x streamed (wave-uniform sWnT reads = broadcast) ----
    float acc[NN];
    #pragma unroll
    for (int n = 0; n < NN; ++n) acc[n] = 0.f;
    #pragma unroll 4
    for (int q = 0; q < DD / 4; ++q) {
        const float4 xv = xr[q];
        #pragma unroll
        for (int n = 0; n < NN; ++n) {
            const float4 w = *(const float4*)&sWnT[n * DD + q * 4];
            acc[n] = fmaf(xv.w, w.w, fmaf(xv.z, w.z,
                     fmaf(xv.y, w.y, fmaf(xv.x, w.x, acc[n]))));
        }
    }
    #pragma unroll
    for (int n = 0; n < NN; ++n) acc[n] += sBn[n];

    // ---- tree expand (leaf bits MSB-first, bit0 = left = +) + argmax ----
    float L2a[4], L3a[8], L4a[16];
    {
        float p = acc[0], m = -acc[0];
        L2a[0] = p + acc[1]; L2a[1] = p - acc[1];
        L2a[2] = m + acc[2]; L2a[3] = m - acc[2];
        #pragma unroll
        for (int i = 0; i < 4; ++i) { L3a[2*i] = L2a[i] + acc[3+i]; L3a[2*i+1] = L2a[i] - acc[3+i]; }
        #pragma unroll
        for (int i = 0; i < 8; ++i) { L4a[2*i] = L3a[i] + acc[7+i]; L4a[2*i+1] = L3a[i] - acc[7+i]; }
    }
    int best = 0; float bv = L4a[0];
    #pragma unroll
    for (int l = 1; l < NL; ++l) if (L4a[l] > bv) { bv = L4a[l]; best = l; }

    // ---- init out accumulators from bias ----
    float4 o0, o1, o2, o3;
    {
        const float4* blv = reinterpret_cast<const float4*>(&sBl[best * OC]);
        o0 = blv[0]; o1 = blv[1]; o2 = blv[2]; o3 = blv[3];
    }
    const int wlofs = best * WSTR;

    // ---- Wl staging geometry: thread t owns leaf t>>4, dim-block t&15 (16 floats) ----
    const float* gw = Wl + ((size_t)(t >> 4) * (DD * OC) + (t & 15) * 16);
    const int stofs = (t >> 4) * WSTR + (t & 15) * 16;

    // ---- phase 3: 8 chunks of 16 dims; single LDS buffer, NO unroll, NO manual pipeline ----
    #pragma unroll 1
    for (int c = 0; c < 8; ++c) {
        // staging load (transient regs; latency overlaps the barrier + other waves' compute)
        const float* g_ = gw + c * 256;
        const float4 s0 = *(const float4*)(g_);
        const float4 s1 = *(const float4*)(g_ + 4);
        const float4 s2 = *(const float4*)(g_ + 8);
        const float4 s3 = *(const float4*)(g_ + 12);

        __syncthreads();   // readers of previous chunk done
        {
            float* d_ = &sWl[stofs];
            *(float4*)(d_)      = s0; *(float4*)(d_ + 4)  = s1;
            *(float4*)(d_ + 8)  = s2; *(float4*)(d_ + 12) = s3;
        }
        __syncthreads();   // chunk c visible

        // x chunk (re-read; one 64B line per lane)
        const float4 xc0 = xr[c * 4 + 0];
        const float4 xc1 = xr[c * 4 + 1];
        const float4 xc2 = xr[c * 4 + 2];
        const float4 xc3 = xr[c * 4 + 3];

        const float* wb = &sWl[wlofs];
        #define KSTEP(xv, k) { \
            const float4 w0 = *(const float4*)&wb[(k) * 16 + 0];  \
            const float4 w1 = *(const float4*)&wb[(k) * 16 + 4];  \
            const float4 w2 = *(const float4*)&wb[(k) * 16 + 8];  \
            const float4 w3 = *(const float4*)&wb[(k) * 16 + 12]; \
            o0.x = fmaf((xv), w0.x, o0.x); o0.y = fmaf((xv), w0.y, o0.y); \
            o0.z = fmaf((xv), w0.z, o0.z); o0.w = fmaf((xv), w0.w, o0.w); \
            o1.x = fmaf((xv), w1.x, o1.x); o1.y = fmaf((xv), w1.y, o1.y); \
            o1.z = fmaf((xv), w1.z, o1.z); o1.w = fmaf((xv), w1.w, o1.w); \
            o2.x = fmaf((xv), w2.x, o2.x); o2.y = fmaf((xv), w2.y, o2.y); \
            o2.z = fmaf((xv), w2.z, o2.z); o2.w = fmaf((xv), w2.w, o2.w); \
            o3.x = fmaf((xv), w3.x, o3.x); o3.y = fmaf((xv), w3.y, o3.y); \
            o3.z = fmaf((xv), w3.z, o3.z); o3.w = fmaf((xv), w3.w, o3.w); }
        KSTEP(xc0.x,  0) KSTEP(xc0.y,  1) KSTEP(xc0.z,  2) KSTEP(xc0.w,  3)
        KSTEP(xc1.x,  4) KSTEP(xc1.y,  5) KSTEP(xc1.z,  6) KSTEP(xc1.w,  7)
        KSTEP(xc2.x,  8) KSTEP(xc2.y,  9) KSTEP(xc2.z, 10) KSTEP(xc2.w, 11)
        KSTEP(xc3.x, 12) KSTEP(xc3.y, 13) KSTEP(xc3.z, 14) KSTEP(xc3.w, 15)
        #undef KSTEP
    }

    // ---- store (coalesced) ----
    if (row < B) {
        size_t ob = (size_t)row * 8;
        *reinterpret_cast<float4*>(&out[ob])     = o0;
        *reinterpret_cast<float4*>(&out[ob + 4]) = o1;

        // log_std = -5 + 3.5*(tanh(v)+1) = -1.5 + 3.5*tanh(v); tanh = 1 - 2/(e^{2v}+1)
        float4 r0, r1;
        #define SQ(v) (-1.5f + 3.5f * (1.f - 2.f / (__expf(2.f * (v)) + 1.f)))
        r0.x = SQ(o2.x); r0.y = SQ(o2.y); r0.z = SQ(o2.z); r0.w = SQ(o2.w);
        r1.x = SQ(o3.x); r1.y = SQ(o3.y); r1.z = SQ(o3.z); r1.w = SQ(o3.w);
        #undef SQ
        size_t ob2 = (size_t)B * 8 + ob;
        *reinterpret_cast<float4*>(&out[ob2])     = r0;
        *reinterpret_cast<float4*>(&out[ob2 + 4]) = r1;
    }
}

extern "C" void kernel_launch(void* const* d_in, const int* in_sizes, int n_in,
                              void* d_out, int out_size, void* d_ws, size_t ws_size,
                              hipStream_t stream)
{
    const float* x  = (const float*)d_in[0];
    const float* Wn = (const float*)d_in[1];
    const float* bn = (const float*)d_in[2];
    const float* Wl = (const float*)d_in[3];
    const float* bl = (const float*)d_in[4];
    float* out = (float*)d_out;

    const int B = in_sizes[0] / DD;              // 262144
    const int blocks = (B + BLK - 1) / BLK;      // 1024

    hipLaunchKernelGGL(dts_fused4, dim3(blocks), dim3(BLK), 0, stream,
                       x, Wn, bn, Wl, bl, out, B);
}